// Round 1
// baseline (162.901 us; speedup 1.0000x reference)
//
#include <hip/hip_runtime.h>

#define BB 16
#define NN 100000
#define KK 8
#define BLOCK 256
#define CHUNKS ((NN + BLOCK - 1) / BLOCK)   // 391

__global__ __launch_bounds__(BLOCK, 8) void lap_loss_kernel(
    const float* __restrict__ geom,
    const float* __restrict__ gtp,
    const int*   __restrict__ idx,
    const float* __restrict__ w,
    float*       __restrict__ out)
{
    // XCD-aware swizzle: xcd = bid%8 (assumed HW round-robin), each XCD owns
    // b = xcd and b = xcd+8 -> per-XCD gather working set ~4.8MB fits L2.
    int bid   = blockIdx.x;
    int xcd   = bid & 7;
    int inner = bid >> 3;                 // 0 .. 2*CHUNKS-1
    int b     = xcd + 8 * (inner / CHUNKS);
    int chunk = inner % CHUNKS;
    int n     = chunk * BLOCK + threadIdx.x;

    float ssq = 0.0f;
    if (n < NN) {
        const float* gb = geom + (size_t)b * NN * 3;
        const float* tb = gtp  + (size_t)b * NN * 3;

        // self term (coalesced: wave reads 768 contiguous bytes per array)
        float dx = gb[n * 3 + 0] - tb[n * 3 + 0];
        float dy = gb[n * 3 + 1] - tb[n * 3 + 1];
        float dz = gb[n * 3 + 2] - tb[n * 3 + 2];

        // idx/w rows: 32B contiguous per thread, vectorized
        const int4*   ip = reinterpret_cast<const int4*>(idx + (size_t)n * KK);
        const float4* wp = reinterpret_cast<const float4*>(w + (size_t)n * KK);
        int4   i0 = ip[0], i1 = ip[1];
        float4 w0 = wp[0], w1 = wp[1];

        int   js[KK] = {i0.x, i0.y, i0.z, i0.w, i1.x, i1.y, i1.z, i1.w};
        float wk[KK] = {w0.x, w0.y, w0.z, w0.w, w1.x, w1.y, w1.z, w1.w};

        #pragma unroll
        for (int k = 0; k < KK; ++k) {
            int j3 = js[k] * 3;
            float wv = wk[k];
            dx += wv * (gb[j3 + 0] - tb[j3 + 0]);
            dy += wv * (gb[j3 + 1] - tb[j3 + 1]);
            dz += wv * (gb[j3 + 2] - tb[j3 + 2]);
        }
        ssq = dx * dx + dy * dy + dz * dz;
    }

    // wave64 reduce
    #pragma unroll
    for (int off = 32; off > 0; off >>= 1)
        ssq += __shfl_down(ssq, off, 64);

    __shared__ float wsum[BLOCK / 64];
    int lane = threadIdx.x & 63;
    int wid  = threadIdx.x >> 6;
    if (lane == 0) wsum[wid] = ssq;
    __syncthreads();

    if (threadIdx.x == 0) {
        float s = 0.0f;
        #pragma unroll
        for (int i = 0; i < BLOCK / 64; ++i) s += wsum[i];
        // pre-scale so atomic partials are small -> negligible rounding
        atomicAdd(out, s * (1.0f / ((float)BB * NN * 3)));
    }
}

extern "C" void kernel_launch(void* const* d_in, const int* in_sizes, int n_in,
                              void* d_out, int out_size, void* d_ws, size_t ws_size,
                              hipStream_t stream) {
    const float* geom = (const float*)d_in[0];
    const float* gtp  = (const float*)d_in[1];
    const int*   idx  = (const int*)d_in[2];
    const float* w    = (const float*)d_in[3];
    float* out = (float*)d_out;

    // harness poisons d_out once and never re-poisons; zero it every call
    hipMemsetAsync(out, 0, sizeof(float), stream);

    dim3 grid(BB * CHUNKS);   // 6256 blocks; swizzle maps bid -> (b, chunk)
    dim3 block(BLOCK);
    lap_loss_kernel<<<grid, block, 0, stream>>>(geom, gtp, idx, w, out);
}

// Round 2
// 57.356 us; speedup vs baseline: 2.8402x; 2.8402x over previous
//
#include <hip/hip_runtime.h>

#define BB 16
#define NN 100000
#define KK 8
#define BLOCK 256
#define CHUNKS ((NN + BLOCK - 1) / BLOCK)   // 391
#define DT_FLOATS (NN * 48)                  // dT[n][b*3+c], 48 floats = 192B per n
#define DT_BYTES ((size_t)DT_FLOATS * 4)     // 19.2 MB

// ---------- Kernel 1: diff + transpose to batch-innermost ----------
// dT[n*48 + b*3 + c] = geom[b][n][c] - gtp[b][n][c]
__global__ __launch_bounds__(BLOCK) void diff_transpose_kernel(
    const float* __restrict__ geom,
    const float* __restrict__ gtp,
    float*       __restrict__ dT)
{
    int v = blockIdx.x * BLOCK + threadIdx.x;   // output float4 index
    if (v >= DT_FLOATS / 4) return;
    int n = v / 12;
    int m = v - n * 12;
    float4 o;
    float* po = &o.x;
    #pragma unroll
    for (int j = 0; j < 4; ++j) {
        int f = m * 4 + j;            // 0..47
        int b = f / 3;
        int c = f - b * 3;
        size_t off = (size_t)b * (NN * 3) + (size_t)n * 3 + c;
        po[j] = geom[off] - gtp[off];
    }
    reinterpret_cast<float4*>(dT)[v] = o;
}

// ---------- Kernel 2: gather + weighted sum + reduce ----------
// 4 threads per vertex n; lane s owns float4 slices {s, s+4, s+8} of the
// 12-float4 row. Group of 4 adjacent lanes covers one 64B line per instr.
__global__ __launch_bounds__(BLOCK, 8) void lap_gather_kernel(
    const float* __restrict__ dT,
    const int*   __restrict__ idx,
    const float* __restrict__ w,
    float*       __restrict__ out)
{
    int t = blockIdx.x * BLOCK + threadIdx.x;
    int n = t >> 2;
    int s = t & 3;

    float ssq = 0.0f;
    if (n < NN) {
        const float4* dv = reinterpret_cast<const float4*>(dT);
        size_t base = (size_t)n * 12 + s;
        float4 a0 = dv[base + 0];
        float4 a1 = dv[base + 4];
        float4 a2 = dv[base + 8];

        const int4*   ip = reinterpret_cast<const int4*>(idx + (size_t)n * KK);
        const float4* wp = reinterpret_cast<const float4*>(w + (size_t)n * KK);
        int4   i0 = ip[0], i1 = ip[1];
        float4 w0 = wp[0], w1 = wp[1];
        int   js[KK] = {i0.x, i0.y, i0.z, i0.w, i1.x, i1.y, i1.z, i1.w};
        float wk[KK] = {w0.x, w0.y, w0.z, w0.w, w1.x, w1.y, w1.z, w1.w};

        #pragma unroll
        for (int k = 0; k < KK; ++k) {
            size_t jb = (size_t)js[k] * 12 + s;
            float4 v0 = dv[jb + 0];
            float4 v1 = dv[jb + 4];
            float4 v2 = dv[jb + 8];
            float wv = wk[k];
            a0.x += wv * v0.x; a0.y += wv * v0.y; a0.z += wv * v0.z; a0.w += wv * v0.w;
            a1.x += wv * v1.x; a1.y += wv * v1.y; a1.z += wv * v1.z; a1.w += wv * v1.w;
            a2.x += wv * v2.x; a2.y += wv * v2.y; a2.z += wv * v2.z; a2.w += wv * v2.w;
        }
        ssq = a0.x*a0.x + a0.y*a0.y + a0.z*a0.z + a0.w*a0.w
            + a1.x*a1.x + a1.y*a1.y + a1.z*a1.z + a1.w*a1.w
            + a2.x*a2.x + a2.y*a2.y + a2.z*a2.z + a2.w*a2.w;
    }

    #pragma unroll
    for (int off = 32; off > 0; off >>= 1)
        ssq += __shfl_down(ssq, off, 64);

    __shared__ float wsum[BLOCK / 64];
    int lane = threadIdx.x & 63;
    int wid  = threadIdx.x >> 6;
    if (lane == 0) wsum[wid] = ssq;
    __syncthreads();

    if (threadIdx.x == 0) {
        float sum = 0.0f;
        #pragma unroll
        for (int i = 0; i < BLOCK / 64; ++i) sum += wsum[i];
        atomicAdd(out, sum * (1.0f / ((float)BB * NN * 3)));
    }
}

// ---------- Fallback (R1 kernel) if ws too small ----------
__global__ __launch_bounds__(BLOCK, 8) void lap_loss_fallback_kernel(
    const float* __restrict__ geom,
    const float* __restrict__ gtp,
    const int*   __restrict__ idx,
    const float* __restrict__ w,
    float*       __restrict__ out)
{
    int bid   = blockIdx.x;
    int xcd   = bid & 7;
    int inner = bid >> 3;
    int b     = xcd + 8 * (inner / CHUNKS);
    int chunk = inner % CHUNKS;
    int n     = chunk * BLOCK + threadIdx.x;

    float ssq = 0.0f;
    if (n < NN) {
        const float* gb = geom + (size_t)b * NN * 3;
        const float* tb = gtp  + (size_t)b * NN * 3;
        float dx = gb[n * 3 + 0] - tb[n * 3 + 0];
        float dy = gb[n * 3 + 1] - tb[n * 3 + 1];
        float dz = gb[n * 3 + 2] - tb[n * 3 + 2];
        const int4*   ip = reinterpret_cast<const int4*>(idx + (size_t)n * KK);
        const float4* wp = reinterpret_cast<const float4*>(w + (size_t)n * KK);
        int4   i0 = ip[0], i1 = ip[1];
        float4 w0 = wp[0], w1 = wp[1];
        int   js[KK] = {i0.x, i0.y, i0.z, i0.w, i1.x, i1.y, i1.z, i1.w};
        float wk[KK] = {w0.x, w0.y, w0.z, w0.w, w1.x, w1.y, w1.z, w1.w};
        #pragma unroll
        for (int k = 0; k < KK; ++k) {
            int j3 = js[k] * 3;
            float wv = wk[k];
            dx += wv * (gb[j3 + 0] - tb[j3 + 0]);
            dy += wv * (gb[j3 + 1] - tb[j3 + 1]);
            dz += wv * (gb[j3 + 2] - tb[j3 + 2]);
        }
        ssq = dx * dx + dy * dy + dz * dz;
    }
    #pragma unroll
    for (int off = 32; off > 0; off >>= 1)
        ssq += __shfl_down(ssq, off, 64);
    __shared__ float wsum[BLOCK / 64];
    int lane = threadIdx.x & 63;
    int wid  = threadIdx.x >> 6;
    if (lane == 0) wsum[wid] = ssq;
    __syncthreads();
    if (threadIdx.x == 0) {
        float sum = 0.0f;
        #pragma unroll
        for (int i = 0; i < BLOCK / 64; ++i) sum += wsum[i];
        atomicAdd(out, sum * (1.0f / ((float)BB * NN * 3)));
    }
}

extern "C" void kernel_launch(void* const* d_in, const int* in_sizes, int n_in,
                              void* d_out, int out_size, void* d_ws, size_t ws_size,
                              hipStream_t stream) {
    const float* geom = (const float*)d_in[0];
    const float* gtp  = (const float*)d_in[1];
    const int*   idx  = (const int*)d_in[2];
    const float* w    = (const float*)d_in[3];
    float* out = (float*)d_out;

    hipMemsetAsync(out, 0, sizeof(float), stream);

    if (ws_size >= DT_BYTES) {
        float* dT = (float*)d_ws;
        int grid1 = (DT_FLOATS / 4 + BLOCK - 1) / BLOCK;        // 4688
        diff_transpose_kernel<<<grid1, BLOCK, 0, stream>>>(geom, gtp, dT);
        int grid2 = (NN * 4 + BLOCK - 1) / BLOCK;               // 1563
        lap_gather_kernel<<<grid2, BLOCK, 0, stream>>>(dT, idx, w, out);
    } else {
        dim3 grid(BB * CHUNKS);
        lap_loss_fallback_kernel<<<grid, BLOCK, 0, stream>>>(geom, gtp, idx, w, out);
    }
}

// Round 3
// 48.915 us; speedup vs baseline: 3.3303x; 1.1726x over previous
//
#include <hip/hip_runtime.h>

#define BB 16
#define NN 100000
#define KK 8
#define BLOCK 256
#define DT_FLOATS (NN * 48)                  // dT[n][b*3+c], 48 floats = 192B per n
#define DT_BYTES ((size_t)DT_FLOATS * 4)     // 19.2 MB
#define GRID2 ((NN * 4 + BLOCK - 1) / BLOCK) // 1563 gather blocks
#define SCALE (1.0f / ((float)BB * NN * 3))

// ---------- Kernel 1: diff + transpose to batch-innermost ----------
// dT[n*48 + b*3 + c] = geom[b][n][c] - gtp[b][n][c]
__global__ __launch_bounds__(BLOCK) void diff_transpose_kernel(
    const float* __restrict__ geom,
    const float* __restrict__ gtp,
    float*       __restrict__ dT)
{
    int v = blockIdx.x * BLOCK + threadIdx.x;   // output float4 index
    if (v >= DT_FLOATS / 4) return;
    int n = v / 12;
    int m = v - n * 12;
    float4 o;
    float* po = &o.x;
    #pragma unroll
    for (int j = 0; j < 4; ++j) {
        int f = m * 4 + j;            // 0..47
        int b = f / 3;
        int c = f - b * 3;
        size_t off = (size_t)b * (NN * 3) + (size_t)n * 3 + c;
        po[j] = geom[off] - gtp[off];
    }
    reinterpret_cast<float4*>(dT)[v] = o;
}

// ---------- Kernel 2: gather + weighted sum + per-block partial ----------
// 4 threads per vertex n; lane s owns float4 slices {s, s+4, s+8} of the
// 12-float4 row. Group of 4 adjacent lanes covers one 64B line per instr.
__global__ __launch_bounds__(BLOCK, 8) void lap_gather_kernel(
    const float* __restrict__ dT,
    const int*   __restrict__ idx,
    const float* __restrict__ w,
    float*       __restrict__ partial)
{
    int t = blockIdx.x * BLOCK + threadIdx.x;
    int n = t >> 2;
    int s = t & 3;

    float ssq = 0.0f;
    if (n < NN) {
        const float4* dv = reinterpret_cast<const float4*>(dT);
        size_t base = (size_t)n * 12 + s;
        float4 a0 = dv[base + 0];
        float4 a1 = dv[base + 4];
        float4 a2 = dv[base + 8];

        const int4*   ip = reinterpret_cast<const int4*>(idx + (size_t)n * KK);
        const float4* wp = reinterpret_cast<const float4*>(w + (size_t)n * KK);
        int4   i0 = ip[0], i1 = ip[1];
        float4 w0 = wp[0], w1 = wp[1];
        int   js[KK] = {i0.x, i0.y, i0.z, i0.w, i1.x, i1.y, i1.z, i1.w};
        float wk[KK] = {w0.x, w0.y, w0.z, w0.w, w1.x, w1.y, w1.z, w1.w};

        #pragma unroll
        for (int k = 0; k < KK; ++k) {
            size_t jb = (size_t)js[k] * 12 + s;
            float4 v0 = dv[jb + 0];
            float4 v1 = dv[jb + 4];
            float4 v2 = dv[jb + 8];
            float wv = wk[k];
            a0.x += wv * v0.x; a0.y += wv * v0.y; a0.z += wv * v0.z; a0.w += wv * v0.w;
            a1.x += wv * v1.x; a1.y += wv * v1.y; a1.z += wv * v1.z; a1.w += wv * v1.w;
            a2.x += wv * v2.x; a2.y += wv * v2.y; a2.z += wv * v2.z; a2.w += wv * v2.w;
        }
        ssq = a0.x*a0.x + a0.y*a0.y + a0.z*a0.z + a0.w*a0.w
            + a1.x*a1.x + a1.y*a1.y + a1.z*a1.z + a1.w*a1.w
            + a2.x*a2.x + a2.y*a2.y + a2.z*a2.z + a2.w*a2.w;
    }

    #pragma unroll
    for (int off = 32; off > 0; off >>= 1)
        ssq += __shfl_down(ssq, off, 64);

    __shared__ float wsum[BLOCK / 64];
    int lane = threadIdx.x & 63;
    int wid  = threadIdx.x >> 6;
    if (lane == 0) wsum[wid] = ssq;
    __syncthreads();

    if (threadIdx.x == 0) {
        float sum = 0.0f;
        #pragma unroll
        for (int i = 0; i < BLOCK / 64; ++i) sum += wsum[i];
        partial[blockIdx.x] = sum;        // plain store, no atomics, no memset
    }
}

// ---------- Kernel 3: final reduce, overwrites out (no zeroing needed) ----------
__global__ __launch_bounds__(BLOCK) void final_reduce_kernel(
    const float* __restrict__ partial,
    float*       __restrict__ out)
{
    float s = 0.0f;
    for (int i = threadIdx.x; i < GRID2; i += BLOCK)
        s += partial[i];

    #pragma unroll
    for (int off = 32; off > 0; off >>= 1)
        s += __shfl_down(s, off, 64);

    __shared__ float wsum[BLOCK / 64];
    int lane = threadIdx.x & 63;
    int wid  = threadIdx.x >> 6;
    if (lane == 0) wsum[wid] = s;
    __syncthreads();

    if (threadIdx.x == 0) {
        float sum = 0.0f;
        #pragma unroll
        for (int i = 0; i < BLOCK / 64; ++i) sum += wsum[i];
        out[0] = sum * SCALE;             // overwrite: deterministic every call
    }
}

extern "C" void kernel_launch(void* const* d_in, const int* in_sizes, int n_in,
                              void* d_out, int out_size, void* d_ws, size_t ws_size,
                              hipStream_t stream) {
    const float* geom = (const float*)d_in[0];
    const float* gtp  = (const float*)d_in[1];
    const int*   idx  = (const int*)d_in[2];
    const float* w    = (const float*)d_in[3];
    float* out = (float*)d_out;

    float* dT      = (float*)d_ws;
    float* partial = (float*)((char*)d_ws + DT_BYTES);

    int grid1 = (DT_FLOATS / 4 + BLOCK - 1) / BLOCK;        // 4688
    diff_transpose_kernel<<<grid1, BLOCK, 0, stream>>>(geom, gtp, dT);
    lap_gather_kernel<<<GRID2, BLOCK, 0, stream>>>(dT, idx, w, partial);
    final_reduce_kernel<<<1, BLOCK, 0, stream>>>(partial, out);
}